// Round 1
// baseline (431.606 us; speedup 1.0000x reference)
//
#include <hip/hip_runtime.h>
#include <math.h>

#define NBATCH 4
#define NSEQ   1024
#define DMODEL 512
#define NH     8
#define DH     64
#define MROWS  (NBATCH*NSEQ)   // 4096
#define MHALF  (DH/2)          // 32

// ---------------------------------------------------------------------------
// Kernel 0: precompute cos/sin tables.
// ang[h,n,m] = pos[n,0]*freqs[h,m,0] + pos[n,1]*freqs[h,m,1]
// layout: cosT[(h*NSEQ + n)*MHALF + m]
// ---------------------------------------------------------------------------
__global__ __launch_bounds__(256) void angles_kernel(
    const float* __restrict__ pos, const float* __restrict__ freqs,
    float* __restrict__ cosT, float* __restrict__ sinT)
{
    int idx = blockIdx.x * 256 + threadIdx.x;   // 0 .. NH*NSEQ*MHALF-1 = 262143
    int m = idx & 31;
    int n = (idx >> 5) & 1023;
    int h = idx >> 15;
    float a = pos[n*2+0] * freqs[(h*MHALF+m)*2+0]
            + pos[n*2+1] * freqs[(h*MHALF+m)*2+1];
    cosT[idx] = cosf(a);
    sinT[idx] = sinf(a);
}

// ---------------------------------------------------------------------------
// Kernel 1: fused QKV GEMM + rotary + transpose.
// A = x (4096 x 512) row-major.  B = one of W_Q/W_K/W_V (512 x 512) row-major.
// Output layout: Qb/Kb/Vb[(b*NH+h)*NSEQ + n][d]  (head-major for attention).
// Q,K get rotary applied in the epilogue (interleaved even/odd storage so the
// plain 64-dim dot product equals qe.ke + qo.ko).
// Grid: x = 24 col-blocks (8 per matrix), y = 64 row-blocks. Block 256 (16x16),
// 4x4 micro-tile, BK=16.
// ---------------------------------------------------------------------------
__global__ __launch_bounds__(256) void qkv_gemm(
    const float* __restrict__ x,
    const float* __restrict__ Wq, const float* __restrict__ Wk,
    const float* __restrict__ Wv,
    const float* __restrict__ cosT, const float* __restrict__ sinT,
    float* __restrict__ Qb, float* __restrict__ Kb, float* __restrict__ Vb)
{
    __shared__ float As[64][17];
    __shared__ float Bs[16][65];

    int cb = blockIdx.x;            // 0..23
    int rb = blockIdx.y;            // 0..63
    int mat = cb >> 3;              // 0=Q 1=K 2=V
    const float* W = (mat == 0) ? Wq : ((mat == 1) ? Wk : Wv);
    int c0 = (cb & 7) * 64;         // col base within the 512-wide matrix
    int r0 = rb * 64;

    int tid = threadIdx.x;
    int tx = tid & 15, ty = tid >> 4;

    float acc[4][4] = {{0.f}};

    for (int k0 = 0; k0 < DMODEL; k0 += 16) {
        #pragma unroll
        for (int i = 0; i < 4; i++) {
            int idx = tid + i * 256;
            int r = idx >> 4, c = idx & 15;
            As[r][c] = x[(r0 + r) * DMODEL + k0 + c];
        }
        #pragma unroll
        for (int i = 0; i < 4; i++) {
            int idx = tid + i * 256;
            int r = idx >> 6, c = idx & 63;
            Bs[r][c] = W[(k0 + r) * DMODEL + c0 + c];
        }
        __syncthreads();
        #pragma unroll
        for (int kk = 0; kk < 16; kk++) {
            float a[4], b[4];
            #pragma unroll
            for (int i = 0; i < 4; i++) a[i] = As[ty*4 + i][kk];
            #pragma unroll
            for (int j = 0; j < 4; j++) b[j] = Bs[kk][tx*4 + j];
            #pragma unroll
            for (int i = 0; i < 4; i++)
                #pragma unroll
                for (int j = 0; j < 4; j++)
                    acc[i][j] += a[i] * b[j];
        }
        __syncthreads();
    }

    // Epilogue: write to [b*NH+h][n][d] layout, rotary for Q/K.
    int colbase = c0 + tx * 4;       // multiple of 4 -> pairs stay in-thread
    int h = colbase >> 6;
    int dbase = colbase & 63;

    #pragma unroll
    for (int i = 0; i < 4; i++) {
        int row = r0 + ty * 4 + i;
        int b = row >> 10, n = row & 1023;
        int obase = ((b * NH + h) * NSEQ + n) * DH;
        if (mat == 2) {
            #pragma unroll
            for (int j = 0; j < 4; j++)
                Vb[obase + dbase + j] = acc[i][j];
        } else {
            float* dst = (mat == 0) ? Qb : Kb;
            #pragma unroll
            for (int p = 0; p < 2; p++) {
                int de = dbase + 2 * p;
                int m = de >> 1;
                float c = cosT[(h * NSEQ + n) * MHALF + m];
                float s = sinT[(h * NSEQ + n) * MHALF + m];
                float ve = acc[i][2*p], vo = acc[i][2*p + 1];
                dst[obase + de]     = ve * c - vo * s;
                dst[obase + de + 1] = ve * s + vo * c;
            }
        }
    }
}

// ---------------------------------------------------------------------------
// Kernel 2: flash-style attention, fp32.
// Grid: x = 16 query tiles (64 q each), y = 32 (b*NH+h). Block 256 (16x16).
// Per thread: 4x4 of S (q x j) and 4x4 of O (q x d).
// ---------------------------------------------------------------------------
__global__ __launch_bounds__(256) void attn_kernel(
    const float* __restrict__ Qb, const float* __restrict__ Kb,
    const float* __restrict__ Vb, float* __restrict__ Ob)
{
    __shared__ float Qs[64][65];
    __shared__ float KVs[64][65];
    __shared__ float Ps[64][65];
    __shared__ float red[64][16];
    __shared__ float mrow[64], lrow[64], arow[64];

    int bh = blockIdx.y;
    int q0 = blockIdx.x * 64;
    int tid = threadIdx.x;
    int tx = tid & 15, ty = tid >> 4;

    const float* Qp = Qb + (size_t)bh * NSEQ * DH;
    const float* Kp = Kb + (size_t)bh * NSEQ * DH;
    const float* Vp = Vb + (size_t)bh * NSEQ * DH;

    #pragma unroll
    for (int i = 0; i < 16; i++) {
        int idx = tid + i * 256;
        int r = idx >> 6, d = idx & 63;
        Qs[r][d] = Qp[(q0 + r) * DH + d];
    }
    if (tid < 64) { mrow[tid] = -INFINITY; lrow[tid] = 0.f; }

    float o[4][4] = {{0.f}};
    const float scale = 0.17677669529663687f;   // (dh/2)^-0.5 = 1/sqrt(32)

    for (int jt = 0; jt < 16; jt++) {
        __syncthreads();   // prior-iteration KVs / red readers done
        #pragma unroll
        for (int i = 0; i < 16; i++) {
            int idx = tid + i * 256;
            int r = idx >> 6, d = idx & 63;
            KVs[r][d] = Kp[(jt * 64 + r) * DH + d];
        }
        __syncthreads();

        // S = scale * Q . K^T   (thread: rows ty*4.., cols tx*4..)
        float s[4][4] = {{0.f}};
        for (int k = 0; k < 64; k++) {
            float qv[4], kv[4];
            #pragma unroll
            for (int i = 0; i < 4; i++) qv[i] = Qs[ty*4 + i][k];
            #pragma unroll
            for (int j = 0; j < 4; j++) kv[j] = KVs[tx*4 + j][k];
            #pragma unroll
            for (int i = 0; i < 4; i++)
                #pragma unroll
                for (int j = 0; j < 4; j++)
                    s[i][j] += qv[i] * kv[j];
        }
        float pm[4];
        #pragma unroll
        for (int i = 0; i < 4; i++) {
            float t = -INFINITY;
            #pragma unroll
            for (int j = 0; j < 4; j++) { s[i][j] *= scale; t = fmaxf(t, s[i][j]); }
            pm[i] = t;
            red[ty*4 + i][tx] = t;
        }
        __syncthreads();
        if (tid < 64) {
            float t = red[tid][0];
            #pragma unroll
            for (int k = 1; k < 16; k++) t = fmaxf(t, red[tid][k]);
            float mold = mrow[tid];
            float mnew = fmaxf(mold, t);
            mrow[tid] = mnew;
            arow[tid] = __expf(mold - mnew);   // 0 on first tile (mold=-inf)
        }
        __syncthreads();

        // P = exp(S - m), stage to LDS; partial row sums.
        float psum[4];
        #pragma unroll
        for (int i = 0; i < 4; i++) {
            float mq = mrow[ty*4 + i];
            float t = 0.f;
            #pragma unroll
            for (int j = 0; j < 4; j++) {
                float p = __expf(s[i][j] - mq);
                Ps[ty*4 + i][tx*4 + j] = p;
                t += p;
            }
            psum[i] = t;
            red[ty*4 + i][tx] = t;
        }
        __syncthreads();
        if (tid < 64) {
            float t = 0.f;
            #pragma unroll
            for (int k = 0; k < 16; k++) t += red[tid][k];
            lrow[tid] = lrow[tid] * arow[tid] + t;
        }
        __syncthreads();   // K reads + Ps/red writes done -> reuse KVs for V

        #pragma unroll
        for (int i = 0; i < 16; i++) {
            int idx = tid + i * 256;
            int r = idx >> 6, d = idx & 63;
            KVs[r][d] = Vp[(jt * 64 + r) * DH + d];
        }
        __syncthreads();

        // O = O*alpha + P.V   (thread: rows ty*4.., dh cols tx*4..)
        float al[4];
        #pragma unroll
        for (int i = 0; i < 4; i++) al[i] = arow[ty*4 + i];
        #pragma unroll
        for (int i = 0; i < 4; i++)
            #pragma unroll
            for (int j = 0; j < 4; j++) o[i][j] *= al[i];
        for (int j = 0; j < 64; j++) {
            float pv[4], vv[4];
            #pragma unroll
            for (int i = 0; i < 4; i++) pv[i] = Ps[ty*4 + i][j];
            #pragma unroll
            for (int jj = 0; jj < 4; jj++) vv[jj] = KVs[j][tx*4 + jj];
            #pragma unroll
            for (int i = 0; i < 4; i++)
                #pragma unroll
                for (int jj = 0; jj < 4; jj++)
                    o[i][jj] += pv[i] * vv[jj];
        }
    }

    // Normalize and write: Ob[(bh)*NSEQ + q][d]
    #pragma unroll
    for (int i = 0; i < 4; i++) {
        float inv = 1.f / lrow[ty*4 + i];
        int n = q0 + ty*4 + i;
        #pragma unroll
        for (int jj = 0; jj < 4; jj++)
            Ob[((size_t)bh * NSEQ + n) * DH + tx*4 + jj] = o[i][jj] * inv;
    }
}

// ---------------------------------------------------------------------------
// Kernel 3: output projection. A[row=(b,n)][k=h*64+d] gathered from Ob
// ([b*NH+h][n][d]); B = W_O (512x512) row-major; out (4096x512).
// ---------------------------------------------------------------------------
__global__ __launch_bounds__(256) void out_gemm(
    const float* __restrict__ Ob, const float* __restrict__ Wo,
    float* __restrict__ out)
{
    __shared__ float As[64][17];
    __shared__ float Bs[16][65];

    int cb = blockIdx.x;      // 0..7
    int rb = blockIdx.y;      // 0..63
    int c0 = cb * 64, r0 = rb * 64;
    int tid = threadIdx.x;
    int tx = tid & 15, ty = tid >> 4;

    float acc[4][4] = {{0.f}};

    for (int k0 = 0; k0 < DMODEL; k0 += 16) {
        int h = k0 >> 6;
        int d0 = k0 & 63;     // BK=16 stays within one head
        #pragma unroll
        for (int i = 0; i < 4; i++) {
            int idx = tid + i * 256;
            int r = idx >> 4, c = idx & 15;
            int row = r0 + r;
            int b = row >> 10, n = row & 1023;
            As[r][c] = Ob[((b * NH + h) * NSEQ + n) * DH + d0 + c];
        }
        #pragma unroll
        for (int i = 0; i < 4; i++) {
            int idx = tid + i * 256;
            int r = idx >> 6, c = idx & 63;
            Bs[r][c] = Wo[(k0 + r) * DMODEL + c0 + c];
        }
        __syncthreads();
        #pragma unroll
        for (int kk = 0; kk < 16; kk++) {
            float a[4], b[4];
            #pragma unroll
            for (int i = 0; i < 4; i++) a[i] = As[ty*4 + i][kk];
            #pragma unroll
            for (int j = 0; j < 4; j++) b[j] = Bs[kk][tx*4 + j];
            #pragma unroll
            for (int i = 0; i < 4; i++)
                #pragma unroll
                for (int j = 0; j < 4; j++)
                    acc[i][j] += a[i] * b[j];
        }
        __syncthreads();
    }

    #pragma unroll
    for (int i = 0; i < 4; i++)
        #pragma unroll
        for (int j = 0; j < 4; j++)
            out[(r0 + ty*4 + i) * DMODEL + c0 + tx*4 + j] = acc[i][j];
}

// ---------------------------------------------------------------------------
extern "C" void kernel_launch(void* const* d_in, const int* in_sizes, int n_in,
                              void* d_out, int out_size, void* d_ws, size_t ws_size,
                              hipStream_t stream) {
    const float* x         = (const float*)d_in[0];
    const float* positions = (const float*)d_in[1];
    const float* Wq        = (const float*)d_in[2];
    const float* Wk        = (const float*)d_in[3];
    const float* Wv        = (const float*)d_in[4];
    const float* Wo        = (const float*)d_in[5];
    // d_in[6] = U : unused — QR of a full-rank square matrix gives a complete
    // orthogonal basis, so P = Uq Uq^T = I and the projection is a no-op.
    const float* freqs     = (const float*)d_in[7];
    float* out = (float*)d_out;

    // workspace layout (floats)
    float* ws   = (float*)d_ws;
    float* cosT = ws;                         // NH*NSEQ*MHALF      = 262144
    float* sinT = cosT + NH*NSEQ*MHALF;       // 262144
    float* Qb   = sinT + NH*NSEQ*MHALF;       // NBATCH*NH*NSEQ*DH  = 2097152
    float* Kb   = Qb + (size_t)NBATCH*NH*NSEQ*DH;
    float* Vb   = Kb + (size_t)NBATCH*NH*NSEQ*DH;
    float* Ob   = Vb + (size_t)NBATCH*NH*NSEQ*DH;

    angles_kernel<<<dim3(NH*NSEQ*MHALF/256), 256, 0, stream>>>(positions, freqs, cosT, sinT);
    qkv_gemm<<<dim3(24, 64), 256, 0, stream>>>(x, Wq, Wk, Wv, cosT, sinT, Qb, Kb, Vb);
    attn_kernel<<<dim3(16, 32), 256, 0, stream>>>(Qb, Kb, Vb, Ob);
    out_gemm<<<dim3(8, 64), 256, 0, stream>>>(Ob, Wo, out);
}

// Round 2
// 286.510 us; speedup vs baseline: 1.5064x; 1.5064x over previous
//
#include <hip/hip_runtime.h>
#include <math.h>

#define NBATCH 4
#define NSEQ   1024
#define DMODEL 512
#define NH     8
#define DH     64
#define MROWS  (NBATCH*NSEQ)   // 4096
#define MHALF  (DH/2)          // 32

typedef __attribute__((ext_vector_type(8))) short bf16x8;
typedef __attribute__((ext_vector_type(4))) float floatx4;

// round-to-nearest-even fp32 -> bf16 (finite inputs only)
__device__ __forceinline__ ushort f2bf(float f) {
    union { float f; uint u; } v; v.f = f;
    uint r = v.u + 0x7fffu + ((v.u >> 16) & 1u);
    return (ushort)(r >> 16);
}

// ---------------------------------------------------------------------------
// Kernel 0: precompute cos/sin tables.
// ang[h,n,m] = pos[n,0]*freqs[h,m,0] + pos[n,1]*freqs[h,m,1]
// ---------------------------------------------------------------------------
__global__ __launch_bounds__(256) void angles_kernel(
    const float* __restrict__ pos, const float* __restrict__ freqs,
    float* __restrict__ cosT, float* __restrict__ sinT)
{
    int idx = blockIdx.x * 256 + threadIdx.x;   // 0 .. NH*NSEQ*MHALF-1
    int m = idx & 31;
    int n = (idx >> 5) & 1023;
    int h = idx >> 15;
    float a = pos[n*2+0] * freqs[(h*MHALF+m)*2+0]
            + pos[n*2+1] * freqs[(h*MHALF+m)*2+1];
    cosT[idx] = cosf(a);
    sinT[idx] = sinf(a);
}

// ---------------------------------------------------------------------------
// Kernel 1: fused QKV GEMM (fp32 compute) + rotary + bf16 pack + transpose.
// Outputs: Qb,Kb bf16 [bh][n][d];  Vt bf16 [bh][d][n] (pre-transposed for PV).
// ---------------------------------------------------------------------------
__global__ __launch_bounds__(256) void qkv_gemm(
    const float* __restrict__ x,
    const float* __restrict__ Wq, const float* __restrict__ Wk,
    const float* __restrict__ Wv,
    const float* __restrict__ cosT, const float* __restrict__ sinT,
    ushort* __restrict__ Qb, ushort* __restrict__ Kb, ushort* __restrict__ Vt)
{
    __shared__ float As[64][17];
    __shared__ float Bs[16][65];

    int cb = blockIdx.x;            // 0..23
    int rb = blockIdx.y;            // 0..63
    int mat = cb >> 3;              // 0=Q 1=K 2=V
    const float* W = (mat == 0) ? Wq : ((mat == 1) ? Wk : Wv);
    int c0 = (cb & 7) * 64;
    int r0 = rb * 64;

    int tid = threadIdx.x;
    int tx = tid & 15, ty = tid >> 4;

    float acc[4][4] = {{0.f}};

    for (int k0 = 0; k0 < DMODEL; k0 += 16) {
        #pragma unroll
        for (int i = 0; i < 4; i++) {
            int idx = tid + i * 256;
            int r = idx >> 4, c = idx & 15;
            As[r][c] = x[(r0 + r) * DMODEL + k0 + c];
        }
        #pragma unroll
        for (int i = 0; i < 4; i++) {
            int idx = tid + i * 256;
            int r = idx >> 6, c = idx & 63;
            Bs[r][c] = W[(k0 + r) * DMODEL + c0 + c];
        }
        __syncthreads();
        #pragma unroll
        for (int kk = 0; kk < 16; kk++) {
            float a[4], b[4];
            #pragma unroll
            for (int i = 0; i < 4; i++) a[i] = As[ty*4 + i][kk];
            #pragma unroll
            for (int j = 0; j < 4; j++) b[j] = Bs[kk][tx*4 + j];
            #pragma unroll
            for (int i = 0; i < 4; i++)
                #pragma unroll
                for (int j = 0; j < 4; j++)
                    acc[i][j] += a[i] * b[j];
        }
        __syncthreads();
    }

    int colbase = c0 + tx * 4;
    int h = colbase >> 6;
    int dbase = colbase & 63;

    if (mat == 2) {
        // V transposed: Vt[(bh*DH + d)*NSEQ + n], pack 4 consecutive n (8B)
        int rowbase = r0 + ty * 4;
        int b = rowbase >> 10, n0 = rowbase & 1023;
        size_t vbase = ((size_t)(b * NH + h) * DH);
        #pragma unroll
        for (int j = 0; j < 4; j++) {
            ushort us[4];
            #pragma unroll
            for (int i = 0; i < 4; i++) us[i] = f2bf(acc[i][j]);
            uint2 pk;
            pk.x = (uint)us[0] | ((uint)us[1] << 16);
            pk.y = (uint)us[2] | ((uint)us[3] << 16);
            *(uint2*)&Vt[(vbase + dbase + j) * NSEQ + n0] = pk;
        }
    } else {
        ushort* dst = (mat == 0) ? Qb : Kb;
        #pragma unroll
        for (int i = 0; i < 4; i++) {
            int row = r0 + ty * 4 + i;
            int b = row >> 10, n = row & 1023;
            float v[4];
            #pragma unroll
            for (int p = 0; p < 2; p++) {
                int de = dbase + 2 * p;
                int m = de >> 1;
                float c = cosT[(h * NSEQ + n) * MHALF + m];
                float s = sinT[(h * NSEQ + n) * MHALF + m];
                float ve = acc[i][2*p], vo = acc[i][2*p + 1];
                v[2*p]     = ve * c - vo * s;
                v[2*p + 1] = ve * s + vo * c;
            }
            uint2 pk;
            pk.x = (uint)f2bf(v[0]) | ((uint)f2bf(v[1]) << 16);
            pk.y = (uint)f2bf(v[2]) | ((uint)f2bf(v[3]) << 16);
            *(uint2*)&dst[((size_t)(b * NH + h) * NSEQ + n) * DH + dbase] = pk;
        }
    }
}

// ---------------------------------------------------------------------------
// Kernel 2: flash attention via bf16 MFMA, computing S^T = K Q^T so that
// the C-frag column (=lane&15) is the query: softmax state is lane-scalar.
// PV done as O^T = V^T P^T with V pre-transposed in global.
// Grid: x = 16 q-tiles (64 q), y = 32 (b*NH+h). Block 256 (4 waves).
// Wave w owns queries q0+16w .. +15 end-to-end. LDS rows padded to 72 bf16
// (144B = 36 dwords) -> bank-balanced b128 access.
// ---------------------------------------------------------------------------
__global__ __launch_bounds__(256) void attn_kernel(
    const ushort* __restrict__ Qb, const ushort* __restrict__ Kb,
    const ushort* __restrict__ Vt, float* __restrict__ Ob)
{
    __shared__ ushort Ks[64 * 72];
    __shared__ ushort Vs[64 * 72];
    __shared__ ushort Ps[64 * 72];

    const int tid = threadIdx.x;
    const int w = tid >> 6, l = tid & 63;
    const int lr = l & 15, lg = l >> 4;
    const int bh = blockIdx.y, q0 = blockIdx.x * 64;

    const ushort* Qg = Qb + (size_t)bh * NSEQ * DH;
    const ushort* Kg = Kb + (size_t)bh * NSEQ * DH;
    const ushort* Vg = Vt + (size_t)bh * DH * NSEQ;

    // Q B-frags for S^T: B[k=d][n=q] = Q[q][d], lane q = lr, d = ks*32+lg*8+jj
    bf16x8 qf[2];
    #pragma unroll
    for (int ks = 0; ks < 2; ks++)
        qf[ks] = *(const bf16x8*)(Qg + (size_t)(q0 + 16*w + lr) * DH + ks*32 + lg*8);

    floatx4 ot[4];
    #pragma unroll
    for (int i = 0; i < 4; i++) ot[i] = (floatx4){0.f, 0.f, 0.f, 0.f};
    float m_run = -INFINITY, l_run = 0.f;
    const float scale = 0.17677669529663687f;   // (dh/2)^-0.5

    const int sr = tid >> 2;          // staging row 0..63
    const int sc = (tid & 3) * 16;    // staging col 0/16/32/48

    for (int jt = 0; jt < 16; jt++) {
        __syncthreads();   // prior tile's consumers done
        {   // stage K tile [j][d] and V^T tile [d][j], bf16, stride 72
            const ushort* kp = Kg + (size_t)(jt*64 + sr) * DH + sc;
            uint4 ka = *(const uint4*)kp;
            uint4 kb = *(const uint4*)(kp + 8);
            *(uint4*)&Ks[sr*72 + sc]     = ka;
            *(uint4*)&Ks[sr*72 + sc + 8] = kb;
            const ushort* vp = Vg + (size_t)sr * NSEQ + jt*64 + sc;
            uint4 va = *(const uint4*)vp;
            uint4 vb = *(const uint4*)(vp + 8);
            *(uint4*)&Vs[sr*72 + sc]     = va;
            *(uint4*)&Vs[sr*72 + sc + 8] = vb;
        }
        __syncthreads();

        // S^T strip: rows j (4 tiles of 16), col q = lr
        floatx4 st[4];
        #pragma unroll
        for (int jm = 0; jm < 4; jm++) {
            floatx4 acc = (floatx4){0.f, 0.f, 0.f, 0.f};
            #pragma unroll
            for (int ks = 0; ks < 2; ks++) {
                bf16x8 af = *(const bf16x8*)&Ks[(jm*16 + lr)*72 + ks*32 + lg*8];
                acc = __builtin_amdgcn_mfma_f32_16x16x32_bf16(af, qf[ks], acc, 0, 0, 0);
            }
            st[jm] = acc;
        }

        // online softmax over j for this lane's q
        float mx = -INFINITY;
        #pragma unroll
        for (int jm = 0; jm < 4; jm++)
            #pragma unroll
            for (int r = 0; r < 4; r++) {
                st[jm][r] *= scale;
                mx = fmaxf(mx, st[jm][r]);
            }
        mx = fmaxf(mx, __shfl_xor(mx, 16, 64));
        mx = fmaxf(mx, __shfl_xor(mx, 32, 64));
        float mnew = fmaxf(m_run, mx);
        float alpha = __expf(m_run - mnew);   // 0 on first tile
        m_run = mnew;

        float rsum = 0.f;
        #pragma unroll
        for (int jm = 0; jm < 4; jm++) {
            ushort us[4];
            #pragma unroll
            for (int r = 0; r < 4; r++) {
                float p = __expf(st[jm][r] - mnew);
                rsum += p;
                us[r] = f2bf(p);
            }
            uint2 pk;
            pk.x = (uint)us[0] | ((uint)us[1] << 16);
            pk.y = (uint)us[2] | ((uint)us[3] << 16);
            // P^T stored as [q_local][j]: 4 consecutive j per lane -> 8B write
            *(uint2*)&Ps[(16*w + lr)*72 + jm*16 + lg*4] = pk;
        }
        rsum += __shfl_xor(rsum, 16, 64);
        rsum += __shfl_xor(rsum, 32, 64);
        l_run = l_run * alpha + rsum;

        #pragma unroll
        for (int dt = 0; dt < 4; dt++)
            #pragma unroll
            for (int r = 0; r < 4; r++)
                ot[dt][r] *= alpha;

        // PV: O^T[d][q] += V^T[d][j] * P^T[j][q]
        // wave-local RAW on Ps (each wave owns rows 16w..16w+15) -> no barrier
        bf16x8 pf[2];
        #pragma unroll
        for (int ks = 0; ks < 2; ks++)
            pf[ks] = *(const bf16x8*)&Ps[(16*w + lr)*72 + ks*32 + lg*8];
        #pragma unroll
        for (int dt = 0; dt < 4; dt++)
            #pragma unroll
            for (int ks = 0; ks < 2; ks++) {
                bf16x8 af = *(const bf16x8*)&Vs[(dt*16 + lr)*72 + ks*32 + lg*8];
                ot[dt] = __builtin_amdgcn_mfma_f32_16x16x32_bf16(af, pf[ks], ot[dt], 0, 0, 0);
            }
    }

    // O^T C-frag: row d = dt*16 + lg*4 + reg, col q = lr -> float4 store per dt
    float inv = 1.f / l_run;
    int n = q0 + 16*w + lr;
    #pragma unroll
    for (int dt = 0; dt < 4; dt++) {
        floatx4 o = ot[dt] * inv;
        *(floatx4*)&Ob[((size_t)bh * NSEQ + n) * DH + dt*16 + lg*4] = o;
    }
}

// ---------------------------------------------------------------------------
// Kernel 3: output projection (fp32). A gathered from Ob [bh][n][d].
// ---------------------------------------------------------------------------
__global__ __launch_bounds__(256) void out_gemm(
    const float* __restrict__ Ob, const float* __restrict__ Wo,
    float* __restrict__ out)
{
    __shared__ float As[64][17];
    __shared__ float Bs[16][65];

    int cb = blockIdx.x;      // 0..7
    int rb = blockIdx.y;      // 0..63
    int c0 = cb * 64, r0 = rb * 64;
    int tid = threadIdx.x;
    int tx = tid & 15, ty = tid >> 4;

    float acc[4][4] = {{0.f}};

    for (int k0 = 0; k0 < DMODEL; k0 += 16) {
        int h = k0 >> 6;
        int d0 = k0 & 63;
        #pragma unroll
        for (int i = 0; i < 4; i++) {
            int idx = tid + i * 256;
            int r = idx >> 4, c = idx & 15;
            int row = r0 + r;
            int b = row >> 10, n = row & 1023;
            As[r][c] = Ob[((size_t)(b * NH + h) * NSEQ + n) * DH + d0 + c];
        }
        #pragma unroll
        for (int i = 0; i < 4; i++) {
            int idx = tid + i * 256;
            int r = idx >> 6, c = idx & 63;
            Bs[r][c] = Wo[(k0 + r) * DMODEL + c0 + c];
        }
        __syncthreads();
        #pragma unroll
        for (int kk = 0; kk < 16; kk++) {
            float a[4], b[4];
            #pragma unroll
            for (int i = 0; i < 4; i++) a[i] = As[ty*4 + i][kk];
            #pragma unroll
            for (int j = 0; j < 4; j++) b[j] = Bs[kk][tx*4 + j];
            #pragma unroll
            for (int i = 0; i < 4; i++)
                #pragma unroll
                for (int j = 0; j < 4; j++)
                    acc[i][j] += a[i] * b[j];
        }
        __syncthreads();
    }

    #pragma unroll
    for (int i = 0; i < 4; i++)
        #pragma unroll
        for (int j = 0; j < 4; j++)
            out[(r0 + ty*4 + i) * DMODEL + c0 + tx*4 + j] = acc[i][j];
}

// ---------------------------------------------------------------------------
extern "C" void kernel_launch(void* const* d_in, const int* in_sizes, int n_in,
                              void* d_out, int out_size, void* d_ws, size_t ws_size,
                              hipStream_t stream) {
    const float* x         = (const float*)d_in[0];
    const float* positions = (const float*)d_in[1];
    const float* Wq        = (const float*)d_in[2];
    const float* Wk        = (const float*)d_in[3];
    const float* Wv        = (const float*)d_in[4];
    const float* Wo        = (const float*)d_in[5];
    // d_in[6] = U : unused — QR of a full-rank square matrix is a complete
    // orthogonal basis, so P = Uq Uq^T = I and the projection is a no-op.
    const float* freqs     = (const float*)d_in[7];
    float* out = (float*)d_out;

    // workspace layout
    float*  ws   = (float*)d_ws;
    float*  cosT = ws;                               // 262144 f32
    float*  sinT = cosT + NH*NSEQ*MHALF;             // 262144 f32
    ushort* Qb   = (ushort*)(sinT + NH*NSEQ*MHALF);  // 2M bf16
    ushort* Kb   = Qb + (size_t)NBATCH*NH*NSEQ*DH;   // 2M bf16
    ushort* Vt   = Kb + (size_t)NBATCH*NH*NSEQ*DH;   // 2M bf16 (transposed)
    float*  Ob   = (float*)(Vt + (size_t)NBATCH*NH*NSEQ*DH);  // 2M f32

    angles_kernel<<<dim3(NH*NSEQ*MHALF/256), 256, 0, stream>>>(positions, freqs, cosT, sinT);
    qkv_gemm<<<dim3(24, 64), 256, 0, stream>>>(x, Wq, Wk, Wv, cosT, sinT, Qb, Kb, Vt);
    attn_kernel<<<dim3(16, 32), 256, 0, stream>>>(Qb, Kb, Vt, Ob);
    out_gemm<<<dim3(8, 64), 256, 0, stream>>>(Ob, Wo, out);
}

// Round 3
// 139.605 us; speedup vs baseline: 3.0916x; 2.0523x over previous
//
#include <hip/hip_runtime.h>
#include <math.h>

#define NBATCH 4
#define NSEQ   1024
#define DMODEL 512
#define NH     8
#define DH     64
#define MROWS  (NBATCH*NSEQ)   // 4096
#define MHALF  (DH/2)          // 32

typedef __attribute__((ext_vector_type(8))) short bf16x8;
typedef __attribute__((ext_vector_type(4))) float floatx4;

// round-to-nearest-even fp32 -> bf16 (finite inputs only)
__device__ __forceinline__ ushort f2bf(float f) {
    union { float f; uint u; } v; v.f = f;
    uint r = v.u + 0x7fffu + ((v.u >> 16) & 1u);
    return (ushort)(r >> 16);
}

// ---------------------------------------------------------------------------
// Kernel 0: cos/sin tables. ang[h,n,m] = pos[n,:]·freqs[h,m,:]
// ---------------------------------------------------------------------------
__global__ __launch_bounds__(256) void angles_kernel(
    const float* __restrict__ pos, const float* __restrict__ freqs,
    float* __restrict__ cosT, float* __restrict__ sinT)
{
    int idx = blockIdx.x * 256 + threadIdx.x;
    int m = idx & 31;
    int n = (idx >> 5) & 1023;
    int h = idx >> 15;
    float a = pos[n*2+0] * freqs[(h*MHALF+m)*2+0]
            + pos[n*2+1] * freqs[(h*MHALF+m)*2+1];
    cosT[idx] = cosf(a);
    sinT[idx] = sinf(a);
}

// ---------------------------------------------------------------------------
// Kernel 0b: x (fp32) -> xb (bf16), 8 elems/thread.
// ---------------------------------------------------------------------------
__global__ __launch_bounds__(256) void xprep_kernel(
    const float* __restrict__ x, ushort* __restrict__ xb)
{
    int idx = (blockIdx.x * 256 + threadIdx.x) * 8;
    float4 a = *(const float4*)&x[idx];
    float4 b = *(const float4*)&x[idx+4];
    uint4 pk;
    pk.x = (uint)f2bf(a.x) | ((uint)f2bf(a.y) << 16);
    pk.y = (uint)f2bf(a.z) | ((uint)f2bf(a.w) << 16);
    pk.z = (uint)f2bf(b.x) | ((uint)f2bf(b.y) << 16);
    pk.w = (uint)f2bf(b.z) | ((uint)f2bf(b.w) << 16);
    *(uint4*)&xb[idx] = pk;
}

// ---------------------------------------------------------------------------
// Kernel 0c: transpose-cast the 4 weight matrices into Wt[n_global][k] bf16.
// n_global: 0..511 Wq, 512..1023 Wk, 1024..1535 Wv, 1536..2047 Wo.
// ---------------------------------------------------------------------------
__global__ __launch_bounds__(256) void wprep_kernel(
    const float* __restrict__ Wq, const float* __restrict__ Wk,
    const float* __restrict__ Wv, const float* __restrict__ Wo,
    ushort* __restrict__ Wt)
{
    __shared__ float T[64][65];
    int n0g = blockIdx.x * 64;          // 0..2047
    int k0  = blockIdx.y * 64;
    int mat = n0g >> 9;
    const float* W = (mat == 0) ? Wq : ((mat == 1) ? Wk : ((mat == 2) ? Wv : Wo));
    int n0 = n0g & 511;
    int tid = threadIdx.x;
    int c = tid & 63, r = tid >> 6;
    #pragma unroll
    for (int i = 0; i < 16; i++)
        T[r + i*4][c] = W[(k0 + r + i*4) * DMODEL + n0 + c];
    __syncthreads();
    int nl = tid >> 2;          // 0..63
    int kg = tid & 3;           // 0..3
    #pragma unroll
    for (int g = 0; g < 4; g++) {
        int kl = kg * 16 + g * 4;
        uint2 pk;
        pk.x = (uint)f2bf(T[kl+0][nl]) | ((uint)f2bf(T[kl+1][nl]) << 16);
        pk.y = (uint)f2bf(T[kl+2][nl]) | ((uint)f2bf(T[kl+3][nl]) << 16);
        *(uint2*)&Wt[(size_t)(n0g + nl) * DMODEL + k0 + kl] = pk;
    }
}

// ---------------------------------------------------------------------------
// Kernel 1: QKV GEMM via bf16 MFMA + rotary + bf16 pack + V-transpose.
// A = xb [4096][512] bf16, B = Wt rows 0..1535 ([n][k] bf16).
// Tile 64x64, 4 waves x four 16x16 C-tiles, BK=32.
// LDS stride 40 bf16 (80B): 16B-aligned b128, <=2-way banks.
// Epilogue bounces C through LDS (fp32) so the rotary pair (even,odd d) is
// adjacent again, then packs bf16 exactly like the verified R2 epilogue.
// ---------------------------------------------------------------------------
__global__ __launch_bounds__(256) void qkv_gemm(
    const ushort* __restrict__ xb, const ushort* __restrict__ Wt,
    const float* __restrict__ cosT, const float* __restrict__ sinT,
    ushort* __restrict__ Qb, ushort* __restrict__ Kb, ushort* __restrict__ Vt)
{
    __shared__ ushort As[64 * 40];
    __shared__ ushort Bs[64 * 40];
    __shared__ float  Cs[64][65];

    const int cb = blockIdx.x;           // 0..23
    const int rb = blockIdx.y;           // 0..63
    const int mat = cb >> 3;             // 0=Q 1=K 2=V
    const int c0 = (cb & 7) * 64;        // col within this matrix
    const int r0 = rb * 64;
    const int ng0 = mat * 512 + c0;      // row base in Wt

    const int tid = threadIdx.x;
    const int w = tid >> 6, l = tid & 63;
    const int lr = l & 15, lg = l >> 4;

    const int srow = tid >> 2;           // staging row 0..63
    const int sgrp = tid & 3;            // k-group of 8

    floatx4 acc[4];
    #pragma unroll
    for (int nt = 0; nt < 4; nt++) acc[nt] = (floatx4){0.f,0.f,0.f,0.f};

    for (int k0 = 0; k0 < DMODEL; k0 += 32) {
        __syncthreads();
        *(uint4*)&As[srow*40 + sgrp*8] =
            *(const uint4*)&xb[(size_t)(r0 + srow) * DMODEL + k0 + sgrp*8];
        *(uint4*)&Bs[srow*40 + sgrp*8] =
            *(const uint4*)&Wt[(size_t)(ng0 + srow) * DMODEL + k0 + sgrp*8];
        __syncthreads();

        bf16x8 af = *(const bf16x8*)&As[(16*w + lr)*40 + lg*8];
        #pragma unroll
        for (int nt = 0; nt < 4; nt++) {
            bf16x8 bf = *(const bf16x8*)&Bs[(nt*16 + lr)*40 + lg*8];
            acc[nt] = __builtin_amdgcn_mfma_f32_16x16x32_bf16(af, bf, acc[nt], 0, 0, 0);
        }
    }

    // C-frags -> LDS (row = M/seq, col = head-dim)
    __syncthreads();
    #pragma unroll
    for (int nt = 0; nt < 4; nt++)
        #pragma unroll
        for (int r = 0; r < 4; r++)
            Cs[16*w + lg*4 + r][nt*16 + lr] = acc[nt][r];
    __syncthreads();

    const int tx = tid & 15, ty = tid >> 4;
    const int dbase = (c0 + tx*4) & 63;  // c0 multiple of 64 -> dbase = tx*4
    const int h = (mat == 2) ? ((c0 + tx*4) >> 6) + 0 : 0;  // placeholder
    const int head = c0 >> 6;            // which head this 64-col tile is
    (void)h;

    if (mat == 2) {
        // Vt[(bh*DH + d)*NSEQ + n], pack 4 consecutive n
        int rowbase = r0 + ty * 4;
        int b = rowbase >> 10, n0 = rowbase & 1023;
        size_t vbase = (size_t)(b * NH + head) * DH;
        #pragma unroll
        for (int j = 0; j < 4; j++) {
            ushort us[4];
            #pragma unroll
            for (int i = 0; i < 4; i++) us[i] = f2bf(Cs[ty*4 + i][tx*4 + j]);
            uint2 pk;
            pk.x = (uint)us[0] | ((uint)us[1] << 16);
            pk.y = (uint)us[2] | ((uint)us[3] << 16);
            *(uint2*)&Vt[(vbase + dbase + j) * NSEQ + n0] = pk;
        }
    } else {
        ushort* dst = (mat == 0) ? Qb : Kb;
        #pragma unroll
        for (int i = 0; i < 4; i++) {
            int row = r0 + ty * 4 + i;
            int b = row >> 10, n = row & 1023;
            float v[4];
            #pragma unroll
            for (int p = 0; p < 2; p++) {
                int de = dbase + 2 * p;
                int m = de >> 1;
                float c = cosT[(head * NSEQ + n) * MHALF + m];
                float s = sinT[(head * NSEQ + n) * MHALF + m];
                float ve = Cs[ty*4 + i][tx*4 + 2*p];
                float vo = Cs[ty*4 + i][tx*4 + 2*p + 1];
                v[2*p]     = ve * c - vo * s;
                v[2*p + 1] = ve * s + vo * c;
            }
            uint2 pk;
            pk.x = (uint)f2bf(v[0]) | ((uint)f2bf(v[1]) << 16);
            pk.y = (uint)f2bf(v[2]) | ((uint)f2bf(v[3]) << 16);
            *(uint2*)&dst[((size_t)(b * NH + head) * NSEQ + n) * DH + dbase] = pk;
        }
    }
}

// ---------------------------------------------------------------------------
// Kernel 2: flash attention via bf16 MFMA (S^T = K Q^T; O^T = V^T P^T).
// Unchanged from R2 except O is stored as bf16 (consumer is a bf16 GEMM).
// ---------------------------------------------------------------------------
__global__ __launch_bounds__(256) void attn_kernel(
    const ushort* __restrict__ Qb, const ushort* __restrict__ Kb,
    const ushort* __restrict__ Vt, ushort* __restrict__ Obb)
{
    __shared__ ushort Ks[64 * 72];
    __shared__ ushort Vs[64 * 72];
    __shared__ ushort Ps[64 * 72];

    const int tid = threadIdx.x;
    const int w = tid >> 6, l = tid & 63;
    const int lr = l & 15, lg = l >> 4;
    const int bh = blockIdx.y, q0 = blockIdx.x * 64;

    const ushort* Qg = Qb + (size_t)bh * NSEQ * DH;
    const ushort* Kg = Kb + (size_t)bh * NSEQ * DH;
    const ushort* Vg = Vt + (size_t)bh * DH * NSEQ;

    bf16x8 qf[2];
    #pragma unroll
    for (int ks = 0; ks < 2; ks++)
        qf[ks] = *(const bf16x8*)(Qg + (size_t)(q0 + 16*w + lr) * DH + ks*32 + lg*8);

    floatx4 ot[4];
    #pragma unroll
    for (int i = 0; i < 4; i++) ot[i] = (floatx4){0.f, 0.f, 0.f, 0.f};
    float m_run = -INFINITY, l_run = 0.f;
    const float scale = 0.17677669529663687f;   // (dh/2)^-0.5

    const int sr = tid >> 2;
    const int sc = (tid & 3) * 16;

    for (int jt = 0; jt < 16; jt++) {
        __syncthreads();
        {
            const ushort* kp = Kg + (size_t)(jt*64 + sr) * DH + sc;
            uint4 ka = *(const uint4*)kp;
            uint4 kb = *(const uint4*)(kp + 8);
            *(uint4*)&Ks[sr*72 + sc]     = ka;
            *(uint4*)&Ks[sr*72 + sc + 8] = kb;
            const ushort* vp = Vg + (size_t)sr * NSEQ + jt*64 + sc;
            uint4 va = *(const uint4*)vp;
            uint4 vb = *(const uint4*)(vp + 8);
            *(uint4*)&Vs[sr*72 + sc]     = va;
            *(uint4*)&Vs[sr*72 + sc + 8] = vb;
        }
        __syncthreads();

        floatx4 st[4];
        #pragma unroll
        for (int jm = 0; jm < 4; jm++) {
            floatx4 acc = (floatx4){0.f, 0.f, 0.f, 0.f};
            #pragma unroll
            for (int ks = 0; ks < 2; ks++) {
                bf16x8 af = *(const bf16x8*)&Ks[(jm*16 + lr)*72 + ks*32 + lg*8];
                acc = __builtin_amdgcn_mfma_f32_16x16x32_bf16(af, qf[ks], acc, 0, 0, 0);
            }
            st[jm] = acc;
        }

        float mx = -INFINITY;
        #pragma unroll
        for (int jm = 0; jm < 4; jm++)
            #pragma unroll
            for (int r = 0; r < 4; r++) {
                st[jm][r] *= scale;
                mx = fmaxf(mx, st[jm][r]);
            }
        mx = fmaxf(mx, __shfl_xor(mx, 16, 64));
        mx = fmaxf(mx, __shfl_xor(mx, 32, 64));
        float mnew = fmaxf(m_run, mx);
        float alpha = __expf(m_run - mnew);
        m_run = mnew;

        float rsum = 0.f;
        #pragma unroll
        for (int jm = 0; jm < 4; jm++) {
            ushort us[4];
            #pragma unroll
            for (int r = 0; r < 4; r++) {
                float p = __expf(st[jm][r] - mnew);
                rsum += p;
                us[r] = f2bf(p);
            }
            uint2 pk;
            pk.x = (uint)us[0] | ((uint)us[1] << 16);
            pk.y = (uint)us[2] | ((uint)us[3] << 16);
            *(uint2*)&Ps[(16*w + lr)*72 + jm*16 + lg*4] = pk;
        }
        rsum += __shfl_xor(rsum, 16, 64);
        rsum += __shfl_xor(rsum, 32, 64);
        l_run = l_run * alpha + rsum;

        #pragma unroll
        for (int dt = 0; dt < 4; dt++)
            #pragma unroll
            for (int r = 0; r < 4; r++)
                ot[dt][r] *= alpha;

        bf16x8 pf[2];
        #pragma unroll
        for (int ks = 0; ks < 2; ks++)
            pf[ks] = *(const bf16x8*)&Ps[(16*w + lr)*72 + ks*32 + lg*8];
        #pragma unroll
        for (int dt = 0; dt < 4; dt++)
            #pragma unroll
            for (int ks = 0; ks < 2; ks++) {
                bf16x8 af = *(const bf16x8*)&Vs[(dt*16 + lr)*72 + ks*32 + lg*8];
                ot[dt] = __builtin_amdgcn_mfma_f32_16x16x32_bf16(af, pf[ks], ot[dt], 0, 0, 0);
            }
    }

    float inv = 1.f / l_run;
    int n = q0 + 16*w + lr;
    #pragma unroll
    for (int dt = 0; dt < 4; dt++) {
        uint2 pk;
        pk.x = (uint)f2bf(ot[dt][0] * inv) | ((uint)f2bf(ot[dt][1] * inv) << 16);
        pk.y = (uint)f2bf(ot[dt][2] * inv) | ((uint)f2bf(ot[dt][3] * inv) << 16);
        *(uint2*)&Obb[((size_t)bh * NSEQ + n) * DH + dt*16 + lg*4] = pk;
    }
}

// ---------------------------------------------------------------------------
// Kernel 3: output projection via bf16 MFMA.
// A gathered from Obb [bh][n][d] bf16; B = Wt rows 1536..2047.
// Same tile structure as qkv_gemm; epilogue bounces C via LDS for
// coalesced float4 stores.
// ---------------------------------------------------------------------------
__global__ __launch_bounds__(256) void out_gemm(
    const ushort* __restrict__ Obb, const ushort* __restrict__ Wt,
    float* __restrict__ out)
{
    __shared__ ushort As[64 * 40];
    __shared__ ushort Bs[64 * 40];
    __shared__ float  Cs[64][65];

    const int cb = blockIdx.x;        // 0..7
    const int rb = blockIdx.y;        // 0..63
    const int c0 = cb * 64, r0 = rb * 64;

    const int tid = threadIdx.x;
    const int w = tid >> 6, l = tid & 63;
    const int lr = l & 15, lg = l >> 4;
    const int srow = tid >> 2;
    const int sgrp = tid & 3;

    const int arow = r0 + srow;
    const int b = arow >> 10, n = arow & 1023;

    floatx4 acc[4];
    #pragma unroll
    for (int nt = 0; nt < 4; nt++) acc[nt] = (floatx4){0.f,0.f,0.f,0.f};

    for (int k0 = 0; k0 < DMODEL; k0 += 32) {
        int h = k0 >> 6;
        int d0 = k0 & 63;
        __syncthreads();
        *(uint4*)&As[srow*40 + sgrp*8] =
            *(const uint4*)&Obb[((size_t)(b * NH + h) * NSEQ + n) * DH + d0 + sgrp*8];
        *(uint4*)&Bs[srow*40 + sgrp*8] =
            *(const uint4*)&Wt[(size_t)(1536 + c0 + srow) * DMODEL + k0 + sgrp*8];
        __syncthreads();

        bf16x8 af = *(const bf16x8*)&As[(16*w + lr)*40 + lg*8];
        #pragma unroll
        for (int nt = 0; nt < 4; nt++) {
            bf16x8 bf = *(const bf16x8*)&Bs[(nt*16 + lr)*40 + lg*8];
            acc[nt] = __builtin_amdgcn_mfma_f32_16x16x32_bf16(af, bf, acc[nt], 0, 0, 0);
        }
    }

    __syncthreads();
    #pragma unroll
    for (int nt = 0; nt < 4; nt++)
        #pragma unroll
        for (int r = 0; r < 4; r++)
            Cs[16*w + lg*4 + r][nt*16 + lr] = acc[nt][r];
    __syncthreads();

    const int tx = tid & 15, ty = tid >> 4;
    #pragma unroll
    for (int i = 0; i < 4; i++) {
        float4 o;
        o.x = Cs[ty*4 + i][tx*4 + 0];
        o.y = Cs[ty*4 + i][tx*4 + 1];
        o.z = Cs[ty*4 + i][tx*4 + 2];
        o.w = Cs[ty*4 + i][tx*4 + 3];
        *(float4*)&out[(size_t)(r0 + ty*4 + i) * DMODEL + c0 + tx*4] = o;
    }
}

// ---------------------------------------------------------------------------
extern "C" void kernel_launch(void* const* d_in, const int* in_sizes, int n_in,
                              void* d_out, int out_size, void* d_ws, size_t ws_size,
                              hipStream_t stream) {
    const float* x         = (const float*)d_in[0];
    const float* positions = (const float*)d_in[1];
    const float* Wq        = (const float*)d_in[2];
    const float* Wk        = (const float*)d_in[3];
    const float* Wv        = (const float*)d_in[4];
    const float* Wo        = (const float*)d_in[5];
    // d_in[6] = U : unused — QR of a full-rank square matrix is a complete
    // orthogonal basis, so P = Uq Uq^T = I and the projection is a no-op.
    const float* freqs     = (const float*)d_in[7];
    float* out = (float*)d_out;

    // workspace layout
    float*  ws   = (float*)d_ws;
    float*  cosT = ws;                                // 262144 f32
    float*  sinT = cosT + NH*NSEQ*MHALF;              // 262144 f32
    ushort* xb   = (ushort*)(sinT + NH*NSEQ*MHALF);   // 2M bf16
    ushort* Wt   = xb + (size_t)MROWS*DMODEL;         // 2048*512 bf16
    ushort* Qb   = Wt + (size_t)2048*DMODEL;          // 2M bf16
    ushort* Kb   = Qb + (size_t)NBATCH*NH*NSEQ*DH;    // 2M bf16
    ushort* Vt   = Kb + (size_t)NBATCH*NH*NSEQ*DH;    // 2M bf16 (transposed)
    ushort* Obb  = Vt + (size_t)NBATCH*NH*NSEQ*DH;    // 2M bf16

    angles_kernel<<<dim3(NH*NSEQ*MHALF/256), 256, 0, stream>>>(positions, freqs, cosT, sinT);
    xprep_kernel<<<dim3(MROWS*DMODEL/(256*8)), 256, 0, stream>>>(x, xb);
    wprep_kernel<<<dim3(32, 8), 256, 0, stream>>>(Wq, Wk, Wv, Wo, Wt);
    qkv_gemm<<<dim3(24, 64), 256, 0, stream>>>(xb, Wt, cosT, sinT, Qb, Kb, Vt);
    attn_kernel<<<dim3(16, 32), 256, 0, stream>>>(Qb, Kb, Vt, Obb);
    out_gemm<<<dim3(8, 64), 256, 0, stream>>>(Obb, Wt, out);
}

// Round 4
// 130.701 us; speedup vs baseline: 3.3022x; 1.0681x over previous
//
#include <hip/hip_runtime.h>
#include <math.h>

#define NBATCH 4
#define NSEQ   1024
#define DMODEL 512
#define NH     8
#define DH     64
#define MROWS  (NBATCH*NSEQ)   // 4096
#define MHALF  (DH/2)          // 32

typedef __attribute__((ext_vector_type(8))) short bf16x8;
typedef __attribute__((ext_vector_type(4))) float floatx4;

// round-to-nearest-even fp32 -> bf16 (finite inputs only)
__device__ __forceinline__ ushort f2bf(float f) {
    union { float f; uint u; } v; v.f = f;
    uint r = v.u + 0x7fffu + ((v.u >> 16) & 1u);
    return (ushort)(r >> 16);
}

// ---------------------------------------------------------------------------
// Kernel 0 (fused prep): blocks 0..1023 angles, 1024..2047 x->bf16,
// 2048..2303 weight transpose-cast into Wt[n_global][k] bf16
// (0..511 Wq, 512..1023 Wk, 1024..1535 Wv, 1536..2047 Wo).
// ---------------------------------------------------------------------------
__global__ __launch_bounds__(256) void prep_kernel(
    const float* __restrict__ pos, const float* __restrict__ freqs,
    const float* __restrict__ x,
    const float* __restrict__ Wq, const float* __restrict__ Wk,
    const float* __restrict__ Wv, const float* __restrict__ Wo,
    float* __restrict__ cosT, float* __restrict__ sinT,
    ushort* __restrict__ xb, ushort* __restrict__ Wt)
{
    __shared__ float T[64][65];
    const int bid = blockIdx.x;
    const int tid = threadIdx.x;

    if (bid < 1024) {
        int idx = bid * 256 + tid;
        int m = idx & 31;
        int n = (idx >> 5) & 1023;
        int h = idx >> 15;
        float a = pos[n*2+0] * freqs[(h*MHALF+m)*2+0]
                + pos[n*2+1] * freqs[(h*MHALF+m)*2+1];
        cosT[idx] = cosf(a);
        sinT[idx] = sinf(a);
    } else if (bid < 2048) {
        int idx = ((bid - 1024) * 256 + tid) * 8;
        float4 a = *(const float4*)&x[idx];
        float4 b = *(const float4*)&x[idx+4];
        uint4 pk;
        pk.x = (uint)f2bf(a.x) | ((uint)f2bf(a.y) << 16);
        pk.y = (uint)f2bf(a.z) | ((uint)f2bf(a.w) << 16);
        pk.z = (uint)f2bf(b.x) | ((uint)f2bf(b.y) << 16);
        pk.w = (uint)f2bf(b.z) | ((uint)f2bf(b.w) << 16);
        *(uint4*)&xb[idx] = pk;
    } else {
        int b2 = bid - 2048;               // 0..255
        int n0g = (b2 & 31) * 64;          // 0..2047
        int k0  = (b2 >> 5) * 64;
        int mat = n0g >> 9;
        const float* W = (mat == 0) ? Wq : ((mat == 1) ? Wk : ((mat == 2) ? Wv : Wo));
        int n0 = n0g & 511;
        int c = tid & 63, r = tid >> 6;
        #pragma unroll
        for (int i = 0; i < 16; i++)
            T[r + i*4][c] = W[(k0 + r + i*4) * DMODEL + n0 + c];
        __syncthreads();
        int nl = tid >> 2;
        int kg = tid & 3;
        #pragma unroll
        for (int g = 0; g < 4; g++) {
            int kl = kg * 16 + g * 4;
            uint2 pk;
            pk.x = (uint)f2bf(T[kl+0][nl]) | ((uint)f2bf(T[kl+1][nl]) << 16);
            pk.y = (uint)f2bf(T[kl+2][nl]) | ((uint)f2bf(T[kl+3][nl]) << 16);
            *(uint2*)&Wt[(size_t)(n0g + nl) * DMODEL + k0 + kl] = pk;
        }
    }
}

// ---------------------------------------------------------------------------
// Kernel 1: QKV GEMM via bf16 MFMA + rotary + bf16 pack + V-transpose.
// (unchanged from R3 — verified)
// ---------------------------------------------------------------------------
__global__ __launch_bounds__(256) void qkv_gemm(
    const ushort* __restrict__ xb, const ushort* __restrict__ Wt,
    const float* __restrict__ cosT, const float* __restrict__ sinT,
    ushort* __restrict__ Qb, ushort* __restrict__ Kb, ushort* __restrict__ Vt)
{
    __shared__ ushort As[64 * 40];
    __shared__ ushort Bs[64 * 40];
    __shared__ float  Cs[64][65];

    const int cb = blockIdx.x;           // 0..23
    const int rb = blockIdx.y;           // 0..63
    const int mat = cb >> 3;             // 0=Q 1=K 2=V
    const int c0 = (cb & 7) * 64;
    const int r0 = rb * 64;
    const int ng0 = mat * 512 + c0;

    const int tid = threadIdx.x;
    const int w = tid >> 6, l = tid & 63;
    const int lr = l & 15, lg = l >> 4;

    const int srow = tid >> 2;
    const int sgrp = tid & 3;

    floatx4 acc[4];
    #pragma unroll
    for (int nt = 0; nt < 4; nt++) acc[nt] = (floatx4){0.f,0.f,0.f,0.f};

    for (int k0 = 0; k0 < DMODEL; k0 += 32) {
        __syncthreads();
        *(uint4*)&As[srow*40 + sgrp*8] =
            *(const uint4*)&xb[(size_t)(r0 + srow) * DMODEL + k0 + sgrp*8];
        *(uint4*)&Bs[srow*40 + sgrp*8] =
            *(const uint4*)&Wt[(size_t)(ng0 + srow) * DMODEL + k0 + sgrp*8];
        __syncthreads();

        bf16x8 af = *(const bf16x8*)&As[(16*w + lr)*40 + lg*8];
        #pragma unroll
        for (int nt = 0; nt < 4; nt++) {
            bf16x8 bf = *(const bf16x8*)&Bs[(nt*16 + lr)*40 + lg*8];
            acc[nt] = __builtin_amdgcn_mfma_f32_16x16x32_bf16(af, bf, acc[nt], 0, 0, 0);
        }
    }

    __syncthreads();
    #pragma unroll
    for (int nt = 0; nt < 4; nt++)
        #pragma unroll
        for (int r = 0; r < 4; r++)
            Cs[16*w + lg*4 + r][nt*16 + lr] = acc[nt][r];
    __syncthreads();

    const int tx = tid & 15, ty = tid >> 4;
    const int dbase = tx * 4;            // c0 multiple of 64
    const int head = c0 >> 6;

    if (mat == 2) {
        int rowbase = r0 + ty * 4;
        int b = rowbase >> 10, n0 = rowbase & 1023;
        size_t vbase = (size_t)(b * NH + head) * DH;
        #pragma unroll
        for (int j = 0; j < 4; j++) {
            ushort us[4];
            #pragma unroll
            for (int i = 0; i < 4; i++) us[i] = f2bf(Cs[ty*4 + i][tx*4 + j]);
            uint2 pk;
            pk.x = (uint)us[0] | ((uint)us[1] << 16);
            pk.y = (uint)us[2] | ((uint)us[3] << 16);
            *(uint2*)&Vt[(vbase + dbase + j) * NSEQ + n0] = pk;
        }
    } else {
        ushort* dst = (mat == 0) ? Qb : Kb;
        #pragma unroll
        for (int i = 0; i < 4; i++) {
            int row = r0 + ty * 4 + i;
            int b = row >> 10, n = row & 1023;
            float v[4];
            #pragma unroll
            for (int p = 0; p < 2; p++) {
                int de = dbase + 2 * p;
                int m = de >> 1;
                float c = cosT[(head * NSEQ + n) * MHALF + m];
                float s = sinT[(head * NSEQ + n) * MHALF + m];
                float ve = Cs[ty*4 + i][tx*4 + 2*p];
                float vo = Cs[ty*4 + i][tx*4 + 2*p + 1];
                v[2*p]     = ve * c - vo * s;
                v[2*p + 1] = ve * s + vo * c;
            }
            uint2 pk;
            pk.x = (uint)f2bf(v[0]) | ((uint)f2bf(v[1]) << 16);
            pk.y = (uint)f2bf(v[2]) | ((uint)f2bf(v[3]) << 16);
            *(uint2*)&dst[((size_t)(b * NH + head) * NSEQ + n) * DH + dbase] = pk;
        }
    }
}

// ---------------------------------------------------------------------------
// Kernel 2: flash attention, split-K x2. Grid (16, 32, 2); block z handles
// j-tiles 8z..8z+7, writes unnormalized O-partial (fp32) + (m,l).
// Register prefetch of next K/V tile overlaps global latency with softmax.
// 4 blocks/CU co-resident (27.6 KB LDS, VGPR<=128 via launch_bounds).
// ---------------------------------------------------------------------------
__global__ __launch_bounds__(256, 4) void attn_kernel(
    const ushort* __restrict__ Qb, const ushort* __restrict__ Kb,
    const ushort* __restrict__ Vt, float* __restrict__ Opart,
    float2* __restrict__ Ml)
{
    __shared__ ushort Ks[64 * 72];
    __shared__ ushort Vs[64 * 72];
    __shared__ ushort Ps[64 * 72];

    const int tid = threadIdx.x;
    const int w = tid >> 6, l = tid & 63;
    const int lr = l & 15, lg = l >> 4;
    const int bh = blockIdx.y, q0 = blockIdx.x * 64;
    const int z = blockIdx.z, jt0 = z * 8;

    const ushort* Qg = Qb + (size_t)bh * NSEQ * DH;
    const ushort* Kg = Kb + (size_t)bh * NSEQ * DH;
    const ushort* Vg = Vt + (size_t)bh * DH * NSEQ;

    bf16x8 qf[2];
    #pragma unroll
    for (int ks = 0; ks < 2; ks++)
        qf[ks] = *(const bf16x8*)(Qg + (size_t)(q0 + 16*w + lr) * DH + ks*32 + lg*8);

    floatx4 ot[4];
    #pragma unroll
    for (int i = 0; i < 4; i++) ot[i] = (floatx4){0.f, 0.f, 0.f, 0.f};
    float m_run = -INFINITY, l_run = 0.f;
    const float scale = 0.17677669529663687f;   // (dh/2)^-0.5

    const int sr = tid >> 2;
    const int sc = (tid & 3) * 16;

    // prefetch first tile
    const ushort* kp = Kg + (size_t)(jt0*64 + sr) * DH + sc;
    uint4 ka  = *(const uint4*)kp;
    uint4 kb2 = *(const uint4*)(kp + 8);
    const ushort* vp = Vg + (size_t)sr * NSEQ + jt0*64 + sc;
    uint4 va  = *(const uint4*)vp;
    uint4 vb2 = *(const uint4*)(vp + 8);

    for (int jt = jt0; jt < jt0 + 8; jt++) {
        __syncthreads();
        *(uint4*)&Ks[sr*72 + sc]     = ka;
        *(uint4*)&Ks[sr*72 + sc + 8] = kb2;
        *(uint4*)&Vs[sr*72 + sc]     = va;
        *(uint4*)&Vs[sr*72 + sc + 8] = vb2;
        __syncthreads();

        if (jt < jt0 + 7) {   // prefetch next tile (uniform branch)
            const ushort* kn = Kg + (size_t)((jt+1)*64 + sr) * DH + sc;
            ka  = *(const uint4*)kn;
            kb2 = *(const uint4*)(kn + 8);
            const ushort* vn = Vg + (size_t)sr * NSEQ + (jt+1)*64 + sc;
            va  = *(const uint4*)vn;
            vb2 = *(const uint4*)(vn + 8);
        }

        floatx4 st[4];
        #pragma unroll
        for (int jm = 0; jm < 4; jm++) {
            floatx4 acc = (floatx4){0.f, 0.f, 0.f, 0.f};
            #pragma unroll
            for (int ks = 0; ks < 2; ks++) {
                bf16x8 af = *(const bf16x8*)&Ks[(jm*16 + lr)*72 + ks*32 + lg*8];
                acc = __builtin_amdgcn_mfma_f32_16x16x32_bf16(af, qf[ks], acc, 0, 0, 0);
            }
            st[jm] = acc;
        }

        float mx = -INFINITY;
        #pragma unroll
        for (int jm = 0; jm < 4; jm++)
            #pragma unroll
            for (int r = 0; r < 4; r++) {
                st[jm][r] *= scale;
                mx = fmaxf(mx, st[jm][r]);
            }
        mx = fmaxf(mx, __shfl_xor(mx, 16, 64));
        mx = fmaxf(mx, __shfl_xor(mx, 32, 64));
        float mnew = fmaxf(m_run, mx);
        float alpha = __expf(m_run - mnew);
        m_run = mnew;

        float rsum = 0.f;
        #pragma unroll
        for (int jm = 0; jm < 4; jm++) {
            ushort us[4];
            #pragma unroll
            for (int r = 0; r < 4; r++) {
                float p = __expf(st[jm][r] - mnew);
                rsum += p;
                us[r] = f2bf(p);
            }
            uint2 pk;
            pk.x = (uint)us[0] | ((uint)us[1] << 16);
            pk.y = (uint)us[2] | ((uint)us[3] << 16);
            *(uint2*)&Ps[(16*w + lr)*72 + jm*16 + lg*4] = pk;
        }
        rsum += __shfl_xor(rsum, 16, 64);
        rsum += __shfl_xor(rsum, 32, 64);
        l_run = l_run * alpha + rsum;

        #pragma unroll
        for (int dt = 0; dt < 4; dt++)
            #pragma unroll
            for (int r = 0; r < 4; r++)
                ot[dt][r] *= alpha;

        bf16x8 pf[2];
        #pragma unroll
        for (int ks = 0; ks < 2; ks++)
            pf[ks] = *(const bf16x8*)&Ps[(16*w + lr)*72 + ks*32 + lg*8];
        #pragma unroll
        for (int dt = 0; dt < 4; dt++)
            #pragma unroll
            for (int ks = 0; ks < 2; ks++) {
                bf16x8 af = *(const bf16x8*)&Vs[(dt*16 + lr)*72 + ks*32 + lg*8];
                ot[dt] = __builtin_amdgcn_mfma_f32_16x16x32_bf16(af, pf[ks], ot[dt], 0, 0, 0);
            }
    }

    // write unnormalized partial + (m,l)
    int n = q0 + 16*w + lr;
    size_t obase = ((size_t)(z * 32 + bh) * NSEQ + n) * DH;
    #pragma unroll
    for (int dt = 0; dt < 4; dt++)
        *(floatx4*)&Opart[obase + dt*16 + lg*4] = ot[dt];
    if (lg == 0)   // all lg lanes hold identical reduced (m,l)
        Ml[(size_t)(z * 32 + bh) * NSEQ + n] = make_float2(m_run, l_run);
}

// ---------------------------------------------------------------------------
// Kernel 2b: combine the two split-K halves -> Obb bf16 [bh][n][d].
// 4 threads per query row (16 d each).
// ---------------------------------------------------------------------------
__global__ __launch_bounds__(256) void combine_kernel(
    const float* __restrict__ Op, const float2* __restrict__ Ml,
    ushort* __restrict__ Obb)
{
    int idx = blockIdx.x * 256 + threadIdx.x;   // 0..131071
    int qi = idx >> 2;                          // bh*NSEQ + n
    int dp = (idx & 3) << 4;
    float2 a = Ml[qi], b = Ml[32768 + qi];
    float m = fmaxf(a.x, b.x);
    float w1 = __expf(a.x - m), w2 = __expf(b.x - m);
    float inv = 1.f / (a.y * w1 + b.y * w2);
    w1 *= inv; w2 *= inv;
    const float* p1 = Op + (size_t)qi * 64 + dp;
    const float* p2 = p1 + (size_t)32768 * 64;
    ushort* po = Obb + (size_t)qi * 64 + dp;
    #pragma unroll
    for (int g = 0; g < 4; g++) {
        float4 u = *(const float4*)(p1 + g*4);
        float4 v = *(const float4*)(p2 + g*4);
        uint2 pk;
        pk.x = (uint)f2bf(u.x*w1 + v.x*w2) | ((uint)f2bf(u.y*w1 + v.y*w2) << 16);
        pk.y = (uint)f2bf(u.z*w1 + v.z*w2) | ((uint)f2bf(u.w*w1 + v.w*w2) << 16);
        *(uint2*)(po + g*4) = pk;
    }
}

// ---------------------------------------------------------------------------
// Kernel 3: output projection via bf16 MFMA (unchanged from R3 — verified).
// ---------------------------------------------------------------------------
__global__ __launch_bounds__(256) void out_gemm(
    const ushort* __restrict__ Obb, const ushort* __restrict__ Wt,
    float* __restrict__ out)
{
    __shared__ ushort As[64 * 40];
    __shared__ ushort Bs[64 * 40];
    __shared__ float  Cs[64][65];

    const int cb = blockIdx.x;
    const int rb = blockIdx.y;
    const int c0 = cb * 64, r0 = rb * 64;

    const int tid = threadIdx.x;
    const int w = tid >> 6, l = tid & 63;
    const int lr = l & 15, lg = l >> 4;
    const int srow = tid >> 2;
    const int sgrp = tid & 3;

    const int arow = r0 + srow;
    const int b = arow >> 10, n = arow & 1023;

    floatx4 acc[4];
    #pragma unroll
    for (int nt = 0; nt < 4; nt++) acc[nt] = (floatx4){0.f,0.f,0.f,0.f};

    for (int k0 = 0; k0 < DMODEL; k0 += 32) {
        int h = k0 >> 6;
        int d0 = k0 & 63;
        __syncthreads();
        *(uint4*)&As[srow*40 + sgrp*8] =
            *(const uint4*)&Obb[((size_t)(b * NH + h) * NSEQ + n) * DH + d0 + sgrp*8];
        *(uint4*)&Bs[srow*40 + sgrp*8] =
            *(const uint4*)&Wt[(size_t)(1536 + c0 + srow) * DMODEL + k0 + sgrp*8];
        __syncthreads();

        bf16x8 af = *(const bf16x8*)&As[(16*w + lr)*40 + lg*8];
        #pragma unroll
        for (int nt = 0; nt < 4; nt++) {
            bf16x8 bf = *(const bf16x8*)&Bs[(nt*16 + lr)*40 + lg*8];
            acc[nt] = __builtin_amdgcn_mfma_f32_16x16x32_bf16(af, bf, acc[nt], 0, 0, 0);
        }
    }

    __syncthreads();
    #pragma unroll
    for (int nt = 0; nt < 4; nt++)
        #pragma unroll
        for (int r = 0; r < 4; r++)
            Cs[16*w + lg*4 + r][nt*16 + lr] = acc[nt][r];
    __syncthreads();

    const int tx = tid & 15, ty = tid >> 4;
    #pragma unroll
    for (int i = 0; i < 4; i++) {
        float4 o;
        o.x = Cs[ty*4 + i][tx*4 + 0];
        o.y = Cs[ty*4 + i][tx*4 + 1];
        o.z = Cs[ty*4 + i][tx*4 + 2];
        o.w = Cs[ty*4 + i][tx*4 + 3];
        *(float4*)&out[(size_t)(r0 + ty*4 + i) * DMODEL + c0 + tx*4] = o;
    }
}

// ---------------------------------------------------------------------------
extern "C" void kernel_launch(void* const* d_in, const int* in_sizes, int n_in,
                              void* d_out, int out_size, void* d_ws, size_t ws_size,
                              hipStream_t stream) {
    const float* x         = (const float*)d_in[0];
    const float* positions = (const float*)d_in[1];
    const float* Wq        = (const float*)d_in[2];
    const float* Wk        = (const float*)d_in[3];
    const float* Wv        = (const float*)d_in[4];
    const float* Wo        = (const float*)d_in[5];
    // d_in[6] = U : unused — QR of a full-rank square matrix is a complete
    // orthogonal basis, so P = Uq Uq^T = I and the projection is a no-op.
    const float* freqs     = (const float*)d_in[7];
    float* out = (float*)d_out;

    // workspace layout
    float*  ws    = (float*)d_ws;
    float*  cosT  = ws;                                 // 262144 f32
    float*  sinT  = cosT + NH*NSEQ*MHALF;               // 262144 f32
    float*  Opart = sinT + NH*NSEQ*MHALF;               // 2*2097152 f32
    float2* Ml    = (float2*)(Opart + 2*(size_t)NBATCH*NH*NSEQ*DH);  // 65536 float2
    ushort* xb    = (ushort*)(Ml + 2*(size_t)NBATCH*NH*NSEQ);        // 2M bf16
    ushort* Wt    = xb + (size_t)MROWS*DMODEL;          // 2048*512 bf16
    ushort* Qb    = Wt + (size_t)2048*DMODEL;
    ushort* Kb    = Qb + (size_t)NBATCH*NH*NSEQ*DH;
    ushort* Vt    = Kb + (size_t)NBATCH*NH*NSEQ*DH;
    ushort* Obb   = Vt + (size_t)NBATCH*NH*NSEQ*DH;

    prep_kernel<<<dim3(2304), 256, 0, stream>>>(positions, freqs, x, Wq, Wk, Wv, Wo,
                                                cosT, sinT, xb, Wt);
    qkv_gemm<<<dim3(24, 64), 256, 0, stream>>>(xb, Wt, cosT, sinT, Qb, Kb, Vt);
    attn_kernel<<<dim3(16, 32, 2), 256, 0, stream>>>(Qb, Kb, Vt, Opart, Ml);
    combine_kernel<<<dim3(512), 256, 0, stream>>>(Opart, Ml, Obb);
    out_gemm<<<dim3(8, 64), 256, 0, stream>>>(Obb, Wt, out);
}